// Round 6
// baseline (1362.485 us; speedup 1.0000x reference)
//
#include <hip/hip_runtime.h>

#define S 2048
#define E 1024
#define H 16
#define D 64
#define KTOP 64
#define RPB 8
#define SCALE 0.125f

// ---------------------------------------------------------------------------
// GEMM: C = A @ W^T + bias.  UNCHANGED (proven correct rounds 2-3); fp32
// vector-ALU, 64x64 tile, BK=32, register double-buffered staging.
// ---------------------------------------------------------------------------
__global__ __launch_bounds__(256) void gemm_nt_bias(
    const float* __restrict__ A,
    const float* __restrict__ W0, const float* __restrict__ W1, const float* __restrict__ W2,
    const float* __restrict__ b0, const float* __restrict__ b1, const float* __restrict__ b2,
    float* __restrict__ C0, float* __restrict__ C1, float* __restrict__ C2)
{
    constexpr int BM = 64, BN = 64, BK = 32;
    const int z = blockIdx.z;
    const float* W    = (z == 0) ? W0 : (z == 1) ? W1 : W2;
    const float* bias = (z == 0) ? b0 : (z == 1) ? b1 : b2;
    float*       C    = (z == 0) ? C0 : (z == 1) ? C1 : C2;

    __shared__ float As[BK][BM + 4];
    __shared__ float Bs[BK][BN + 4];

    const int tid = threadIdx.x;
    const int tx = tid & 15;
    const int ty = tid >> 4;
    const int m0 = blockIdx.y * BM;
    const int n0 = blockIdx.x * BN;

    const int r0 = tid >> 3;
    const int r1 = (tid + 256) >> 3;
    const int cq = tid & 7;

    float acc[4][4] = {};
    float4 av0, av1, wv0, wv1;

    {
        const int k0 = 0;
        av0 = *(const float4*)&A[(size_t)(m0 + r0) * E + k0 + cq * 4];
        av1 = *(const float4*)&A[(size_t)(m0 + r1) * E + k0 + cq * 4];
        wv0 = *(const float4*)&W[(size_t)(n0 + r0) * E + k0 + cq * 4];
        wv1 = *(const float4*)&W[(size_t)(n0 + r1) * E + k0 + cq * 4];
    }

    for (int k0 = 0; k0 < E; k0 += BK) {
        __syncthreads();
        As[cq * 4 + 0][r0] = av0.x; As[cq * 4 + 1][r0] = av0.y;
        As[cq * 4 + 2][r0] = av0.z; As[cq * 4 + 3][r0] = av0.w;
        As[cq * 4 + 0][r1] = av1.x; As[cq * 4 + 1][r1] = av1.y;
        As[cq * 4 + 2][r1] = av1.z; As[cq * 4 + 3][r1] = av1.w;
        Bs[cq * 4 + 0][r0] = wv0.x; Bs[cq * 4 + 1][r0] = wv0.y;
        Bs[cq * 4 + 2][r0] = wv0.z; Bs[cq * 4 + 3][r0] = wv0.w;
        Bs[cq * 4 + 0][r1] = wv1.x; Bs[cq * 4 + 1][r1] = wv1.y;
        Bs[cq * 4 + 2][r1] = wv1.z; Bs[cq * 4 + 3][r1] = wv1.w;
        __syncthreads();

        if (k0 + BK < E) {
            const int kn = k0 + BK;
            av0 = *(const float4*)&A[(size_t)(m0 + r0) * E + kn + cq * 4];
            av1 = *(const float4*)&A[(size_t)(m0 + r1) * E + kn + cq * 4];
            wv0 = *(const float4*)&W[(size_t)(n0 + r0) * E + kn + cq * 4];
            wv1 = *(const float4*)&W[(size_t)(n0 + r1) * E + kn + cq * 4];
        }

#pragma unroll
        for (int k = 0; k < BK; ++k) {
            const float4 a4 = *(const float4*)&As[k][ty * 4];
            const float4 b4 = *(const float4*)&Bs[k][tx * 4];
            const float aa[4] = {a4.x, a4.y, a4.z, a4.w};
            const float bb[4] = {b4.x, b4.y, b4.z, b4.w};
#pragma unroll
            for (int i = 0; i < 4; ++i)
#pragma unroll
                for (int j = 0; j < 4; ++j)
                    acc[i][j] = fmaf(aa[i], bb[j], acc[i][j]);
        }
    }

    const float4 bv = *(const float4*)&bias[n0 + tx * 4];
#pragma unroll
    for (int i = 0; i < 4; ++i) {
        float4 o;
        o.x = acc[i][0] + bv.x; o.y = acc[i][1] + bv.y;
        o.z = acc[i][2] + bv.z; o.w = acc[i][3] + bv.w;
        *(float4*)&C[(size_t)(m0 + ty * 4 + i) * E + n0 + tx * 4] = o;
    }
}

// ---------------------------------------------------------------------------
// Fused top-k attention, restructured (round 4) to eliminate register spill:
//   - thread t owns key (c*256+t); its K-row lives in 64 VGPRs (kf[16] float4)
//   - Q read via wave-uniform addresses -> scalar loads (broadcast, no LDS)
//   - scores written straight to LDS scoreBuf[8][2048] (stride-1, conflict-
//     free); only 8 accumulators live -> peak ~95 VGPRs, no spill
//   - selection: wave w handles rows 2w,2w+1; lane l loads keys {64j+l}
//     (32 regs), then the proven ballot binary-search; selection->PV is
//     wave-local (rz stays in registers, no extra barrier)
// WG = 256 threads = 8 query rows of one head; grid (S/8=256) x (H=16).
// ---------------------------------------------------------------------------
__device__ __forceinline__ unsigned sortable_u(float f) {
    unsigned u = __float_as_uint(f);
    return (u & 0x80000000u) ? ~u : (u | 0x80000000u);
}
__device__ __forceinline__ float unsortable_f(unsigned su) {
    unsigned u = (su & 0x80000000u) ? (su & 0x7fffffffu) : ~su;
    return __uint_as_float(u);
}

__global__ __launch_bounds__(256) void topk_attn(
    const float* __restrict__ Qp, const float* __restrict__ Kp,
    const float* __restrict__ Vp, float* __restrict__ AO)
{
    constexpr int CHUNK = 256;      // keys per chunk (= threads)
    constexpr int NCH = S / CHUNK;  // 8

    __shared__ float scoreBuf[RPB][S];   // 64 KB
    __shared__ int   sIdx[RPB][KTOP];    // 2 KB
    __shared__ float sW[RPB][KTOP];      // 2 KB

    const int tid  = threadIdx.x;
    const int lane = tid & 63;
    const int wv   = tid >> 6;
    const int h    = blockIdx.y;
    const int q0   = blockIdx.x * RPB;

    // ---- Phase 1: scores.  8 chunks of 256 keys; one key per thread. ----
    const float* Qh = Qp + (size_t)q0 * E + h * D;   // wave-uniform base
#pragma unroll 1
    for (int c = 0; c < NCH; ++c) {
        const int key = c * CHUNK + tid;
        const float* krow = Kp + (size_t)key * E + h * D;
        float4 kf[16];
#pragma unroll
        for (int i = 0; i < 16; ++i) kf[i] = *(const float4*)&krow[4 * i];

        float s[RPB];
#pragma unroll
        for (int r = 0; r < RPB; ++r) s[r] = 0.f;

#pragma unroll
        for (int i = 0; i < 16; ++i) {
#pragma unroll
            for (int r = 0; r < RPB; ++r) {
                const float4 q4 = *(const float4*)&Qh[(size_t)r * E + 4 * i];  // uniform -> s_load
                s[r] = fmaf(q4.x, kf[i].x, s[r]);
                s[r] = fmaf(q4.y, kf[i].y, s[r]);
                s[r] = fmaf(q4.z, kf[i].z, s[r]);
                s[r] = fmaf(q4.w, kf[i].w, s[r]);
            }
        }
#pragma unroll
        for (int r = 0; r < RPB; ++r) scoreBuf[r][key] = s[r] * SCALE;
    }

    __syncthreads();   // all scores published

    // ---- Phase 2: per-wave top-64 for rows 2w, 2w+1 ----
    const unsigned long long below = (1ull << lane) - 1ull;
    float rzv[2];

#pragma unroll
    for (int rr = 0; rr < 2; ++rr) {
        const int row = wv * 2 + rr;

        unsigned su[32];
        unsigned mx = 0u;
#pragma unroll
        for (int j = 0; j < 32; ++j) {
            const unsigned v = sortable_u(scoreBuf[row][j * 64 + lane]);
            su[j] = v;
            if (v > mx) mx = v;
        }
        // wave max
#pragma unroll
        for (int o = 32; o; o >>= 1) {
            const unsigned t = (unsigned)__shfl_xor((int)mx, o, 64);
            if (t > mx) mx = t;
        }
        const float rowmax = unsortable_f(mx);

        // bitwise binary search: T = max t with count(su >= t) >= KTOP
        unsigned T = 0u;
        for (int b = 31; b >= 0; --b) {
            const unsigned cand = T | (1u << b);
            int cnt = 0;
#pragma unroll
            for (int j = 0; j < 32; ++j)
                cnt += (int)__popcll(__ballot(su[j] >= cand));
            if (cnt >= KTOP) {
                T = cand;
                if (cnt == KTOP) break;
            }
        }

        // gather strictly-greater, then ties (==T) up to capacity.
        // enumeration order (j asc, lane asc) == ascending key -> matches
        // jax.lax.top_k's lowest-index tie preference.
        int cprev = 0;
        float zs = 0.f;
#pragma unroll
        for (int j = 0; j < 32; ++j) {
            const bool sel = (su[j] > T);
            const unsigned long long mk = __ballot(sel);
            if (sel) {
                const int pos = cprev + (int)__popcll(mk & below);
                const float w = __expf(unsortable_f(su[j]) - rowmax);
                sIdx[row][pos] = (j << 6) | lane;
                sW[row][pos] = w;
                zs += w;
            }
            cprev += (int)__popcll(mk);
        }
#pragma unroll
        for (int j = 0; j < 32; ++j) {
            const bool sel = (su[j] == T);
            const unsigned long long mk = __ballot(sel);
            if (sel) {
                const int pos = cprev + (int)__popcll(mk & below);
                if (pos < KTOP) {
                    const float w = __expf(unsortable_f(su[j]) - rowmax);
                    sIdx[row][pos] = (j << 6) | lane;
                    sW[row][pos] = w;
                    zs += w;   // kept ties count in the denominator
                }
            }
            cprev += (int)__popcll(mk);
        }
#pragma unroll
        for (int o = 32; o; o >>= 1) zs += __shfl_xor(zs, o, 64);
        rzv[rr] = zs;
    }

    // ---- Phase 3: PV gather (wave-local; same wave wrote sIdx/sW rows) ----
    const float* Vh = Vp + h * D + lane;
    const int rowA = wv * 2, rowB = wv * 2 + 1;
    float pva = 0.f, pvb = 0.f;
#pragma unroll 4
    for (int j = 0; j < KTOP; ++j) {
        pva = fmaf(sW[rowA][j], Vh[(size_t)sIdx[rowA][j] * E], pva);
        pvb = fmaf(sW[rowB][j], Vh[(size_t)sIdx[rowB][j] * E], pvb);
    }
    AO[(size_t)(q0 + rowA) * E + h * D + lane] = pva / rzv[0];
    AO[(size_t)(q0 + rowB) * E + h * D + lane] = pvb / rzv[1];
}

// ---------------------------------------------------------------------------
extern "C" void kernel_launch(void* const* d_in, const int* in_sizes, int n_in,
                              void* d_out, int out_size, void* d_ws, size_t ws_size,
                              hipStream_t stream) {
    const float* x  = (const float*)d_in[0];
    const float* Wq = (const float*)d_in[1];
    const float* bq = (const float*)d_in[2];
    const float* Wk = (const float*)d_in[3];
    const float* bk = (const float*)d_in[4];
    const float* Wv = (const float*)d_in[5];
    const float* bv = (const float*)d_in[6];
    const float* Wo = (const float*)d_in[7];
    const float* bo = (const float*)d_in[8];
    float* out = (float*)d_out;

    float* Qp = (float*)d_ws;          // S*E fp32 = 8 MB each
    float* Kp = Qp + (size_t)S * E;
    float* Vp = Kp + (size_t)S * E;
    float* AO = Vp + (size_t)S * E;    // total 32 MB of ws

    const dim3 blk(256);
    gemm_nt_bias<<<dim3(E / 64, S / 64, 3), blk, 0, stream>>>(
        x, Wq, Wk, Wv, bq, bk, bv, Qp, Kp, Vp);
    topk_attn<<<dim3(S / RPB, H), blk, 0, stream>>>(Qp, Kp, Vp, AO);
    gemm_nt_bias<<<dim3(E / 64, S / 64, 1), blk, 0, stream>>>(
        AO, Wo, Wo, Wo, bo, bo, bo, out, out, out);
}

// Round 8
// 1293.892 us; speedup vs baseline: 1.0530x; 1.0530x over previous
//
#include <hip/hip_runtime.h>

#define S 2048
#define E 1024
#define H 16
#define D 64
#define KTOP 64
#define RPB 8
#define SCALE 0.125f

// ---------------------------------------------------------------------------
// GEMM: C = A @ W^T + bias.  UNCHANGED (proven correct rounds 2-6); fp32
// vector-ALU, 64x64 tile, BK=32, register double-buffered staging.
// ---------------------------------------------------------------------------
__global__ __launch_bounds__(256) void gemm_nt_bias(
    const float* __restrict__ A,
    const float* __restrict__ W0, const float* __restrict__ W1, const float* __restrict__ W2,
    const float* __restrict__ b0, const float* __restrict__ b1, const float* __restrict__ b2,
    float* __restrict__ C0, float* __restrict__ C1, float* __restrict__ C2)
{
    constexpr int BM = 64, BN = 64, BK = 32;
    const int z = blockIdx.z;
    const float* W    = (z == 0) ? W0 : (z == 1) ? W1 : W2;
    const float* bias = (z == 0) ? b0 : (z == 1) ? b1 : b2;
    float*       C    = (z == 0) ? C0 : (z == 1) ? C1 : C2;

    __shared__ float As[BK][BM + 4];
    __shared__ float Bs[BK][BN + 4];

    const int tid = threadIdx.x;
    const int tx = tid & 15;
    const int ty = tid >> 4;
    const int m0 = blockIdx.y * BM;
    const int n0 = blockIdx.x * BN;

    const int r0 = tid >> 3;
    const int r1 = (tid + 256) >> 3;
    const int cq = tid & 7;

    float acc[4][4] = {};
    float4 av0, av1, wv0, wv1;

    {
        const int k0 = 0;
        av0 = *(const float4*)&A[(size_t)(m0 + r0) * E + k0 + cq * 4];
        av1 = *(const float4*)&A[(size_t)(m0 + r1) * E + k0 + cq * 4];
        wv0 = *(const float4*)&W[(size_t)(n0 + r0) * E + k0 + cq * 4];
        wv1 = *(const float4*)&W[(size_t)(n0 + r1) * E + k0 + cq * 4];
    }

    for (int k0 = 0; k0 < E; k0 += BK) {
        __syncthreads();
        As[cq * 4 + 0][r0] = av0.x; As[cq * 4 + 1][r0] = av0.y;
        As[cq * 4 + 2][r0] = av0.z; As[cq * 4 + 3][r0] = av0.w;
        As[cq * 4 + 0][r1] = av1.x; As[cq * 4 + 1][r1] = av1.y;
        As[cq * 4 + 2][r1] = av1.z; As[cq * 4 + 3][r1] = av1.w;
        Bs[cq * 4 + 0][r0] = wv0.x; Bs[cq * 4 + 1][r0] = wv0.y;
        Bs[cq * 4 + 2][r0] = wv0.z; Bs[cq * 4 + 3][r0] = wv0.w;
        Bs[cq * 4 + 0][r1] = wv1.x; Bs[cq * 4 + 1][r1] = wv1.y;
        Bs[cq * 4 + 2][r1] = wv1.z; Bs[cq * 4 + 3][r1] = wv1.w;
        __syncthreads();

        if (k0 + BK < E) {
            const int kn = k0 + BK;
            av0 = *(const float4*)&A[(size_t)(m0 + r0) * E + kn + cq * 4];
            av1 = *(const float4*)&A[(size_t)(m0 + r1) * E + kn + cq * 4];
            wv0 = *(const float4*)&W[(size_t)(n0 + r0) * E + kn + cq * 4];
            wv1 = *(const float4*)&W[(size_t)(n0 + r1) * E + kn + cq * 4];
        }

#pragma unroll
        for (int k = 0; k < BK; ++k) {
            const float4 a4 = *(const float4*)&As[k][ty * 4];
            const float4 b4 = *(const float4*)&Bs[k][tx * 4];
            const float aa[4] = {a4.x, a4.y, a4.z, a4.w};
            const float bb[4] = {b4.x, b4.y, b4.z, b4.w};
#pragma unroll
            for (int i = 0; i < 4; ++i)
#pragma unroll
                for (int j = 0; j < 4; ++j)
                    acc[i][j] = fmaf(aa[i], bb[j], acc[i][j]);
        }
    }

    const float4 bv = *(const float4*)&bias[n0 + tx * 4];
#pragma unroll
    for (int i = 0; i < 4; ++i) {
        float4 o;
        o.x = acc[i][0] + bv.x; o.y = acc[i][1] + bv.y;
        o.z = acc[i][2] + bv.z; o.w = acc[i][3] + bv.w;
        *(float4*)&C[(size_t)(m0 + ty * 4 + i) * E + n0 + tx * 4] = o;
    }
}

// ---------------------------------------------------------------------------
// Fused top-k attention (round 7, resubmitted round 8 after infra failure).
//   Round-6 evidence: spill dead (VGPR 88, WRITE 8MB) but dur 1097us,
//   VALUBusy 87%, SGPR 112 -> the global "uniform" Q loads became mass
//   s_load batches serialized by lgkmcnt waits at 1.9 waves/SIMD.
//   Fix: Q staged ONCE in Qlds[8][64] (2KB); score loop reads it via
//   wave-uniform ds_read_b128 (same-address broadcast, conflict-free,
//   LDS pipe overlaps VALU).  K stays in registers (kf[16], per-thread
//   key).  Scores -> scoreBuf stride-1.  Phases 2/3 unchanged.
// WG = 256 threads = 8 query rows of one head; grid (S/8=256) x (H=16).
// ---------------------------------------------------------------------------
__device__ __forceinline__ unsigned sortable_u(float f) {
    unsigned u = __float_as_uint(f);
    return (u & 0x80000000u) ? ~u : (u | 0x80000000u);
}
__device__ __forceinline__ float unsortable_f(unsigned su) {
    unsigned u = (su & 0x80000000u) ? (su & 0x7fffffffu) : ~su;
    return __uint_as_float(u);
}

__global__ __launch_bounds__(256) void topk_attn(
    const float* __restrict__ Qp, const float* __restrict__ Kp,
    const float* __restrict__ Vp, float* __restrict__ AO)
{
    constexpr int CHUNK = 256;      // keys per chunk (= threads)
    constexpr int NCH = S / CHUNK;  // 8

    __shared__ float scoreBuf[RPB][S];   // 64 KB
    __shared__ float Qlds[RPB][D];       // 2 KB, pre-scaled Q rows
    __shared__ int   sIdx[RPB][KTOP];    // 2 KB
    __shared__ float sW[RPB][KTOP];      // 2 KB

    const int tid  = threadIdx.x;
    const int lane = tid & 63;
    const int wv   = tid >> 6;
    const int h    = blockIdx.y;
    const int q0   = blockIdx.x * RPB;

    // ---- stage Q (pre-scaled), once ----
    if (tid < RPB * (D / 4)) {          // 128 threads, one float4 each
        const int r = tid >> 4, cq4 = tid & 15;
        float4 qv = *(const float4*)&Qp[(size_t)(q0 + r) * E + h * D + cq4 * 4];
        qv.x *= SCALE; qv.y *= SCALE; qv.z *= SCALE; qv.w *= SCALE;
        *(float4*)&Qlds[r][cq4 * 4] = qv;
    }
    __syncthreads();

    // ---- Phase 1: scores.  8 chunks of 256 keys; one key per thread. ----
#pragma unroll 1
    for (int c = 0; c < NCH; ++c) {
        const int key = c * CHUNK + tid;
        const float* krow = Kp + (size_t)key * E + h * D;
        float4 kf[16];
#pragma unroll
        for (int i = 0; i < 16; ++i) kf[i] = *(const float4*)&krow[4 * i];

        float s[RPB];
#pragma unroll
        for (int r = 0; r < RPB; ++r) s[r] = 0.f;

#pragma unroll
        for (int i = 0; i < 16; ++i) {
#pragma unroll
            for (int r = 0; r < RPB; ++r) {
                // wave-uniform LDS address -> broadcast ds_read_b128
                const float4 q4 = *(const float4*)&Qlds[r][4 * i];
                s[r] = fmaf(q4.x, kf[i].x, s[r]);
                s[r] = fmaf(q4.y, kf[i].y, s[r]);
                s[r] = fmaf(q4.z, kf[i].z, s[r]);
                s[r] = fmaf(q4.w, kf[i].w, s[r]);
            }
        }
#pragma unroll
        for (int r = 0; r < RPB; ++r) scoreBuf[r][key] = s[r];
    }

    __syncthreads();   // all scores published

    // ---- Phase 2: per-wave top-64 for rows 2w, 2w+1 ----
    const unsigned long long below = (1ull << lane) - 1ull;
    float rzv[2];

#pragma unroll
    for (int rr = 0; rr < 2; ++rr) {
        const int row = wv * 2 + rr;

        unsigned su[32];
        unsigned mx = 0u;
#pragma unroll
        for (int j = 0; j < 32; ++j) {
            const unsigned v = sortable_u(scoreBuf[row][j * 64 + lane]);
            su[j] = v;
            if (v > mx) mx = v;
        }
        // wave max
#pragma unroll
        for (int o = 32; o; o >>= 1) {
            const unsigned t = (unsigned)__shfl_xor((int)mx, o, 64);
            if (t > mx) mx = t;
        }
        const float rowmax = unsortable_f(mx);

        // bitwise binary search: T = max t with count(su >= t) >= KTOP
        unsigned T = 0u;
        for (int b = 31; b >= 0; --b) {
            const unsigned cand = T | (1u << b);
            int cnt = 0;
#pragma unroll
            for (int j = 0; j < 32; ++j)
                cnt += (int)__popcll(__ballot(su[j] >= cand));
            if (cnt >= KTOP) {
                T = cand;
                if (cnt == KTOP) break;
            }
        }

        // gather strictly-greater, then ties (==T) up to capacity.
        // enumeration order (j asc, lane asc) == ascending key -> same
        // selected SET as jax.lax.top_k (stable, lowest-index ties).
        int cprev = 0;
        float zs = 0.f;
#pragma unroll
        for (int j = 0; j < 32; ++j) {
            const bool sel = (su[j] > T);
            const unsigned long long mk = __ballot(sel);
            if (sel) {
                const int pos = cprev + (int)__popcll(mk & below);
                const float w = __expf(unsortable_f(su[j]) - rowmax);
                sIdx[row][pos] = (j << 6) | lane;
                sW[row][pos] = w;
                zs += w;
            }
            cprev += (int)__popcll(mk);
        }
#pragma unroll
        for (int j = 0; j < 32; ++j) {
            const bool sel = (su[j] == T);
            const unsigned long long mk = __ballot(sel);
            if (sel) {
                const int pos = cprev + (int)__popcll(mk & below);
                if (pos < KTOP) {
                    const float w = __expf(unsortable_f(su[j]) - rowmax);
                    sIdx[row][pos] = (j << 6) | lane;
                    sW[row][pos] = w;
                    zs += w;   // kept ties count in the denominator
                }
            }
            cprev += (int)__popcll(mk);
        }
#pragma unroll
        for (int o = 32; o; o >>= 1) zs += __shfl_xor(zs, o, 64);
        rzv[rr] = zs;
    }

    // ---- Phase 3: PV gather (wave-local; same wave wrote sIdx/sW rows) ----
    const float* Vh = Vp + h * D + lane;
    const int rowA = wv * 2, rowB = wv * 2 + 1;
    float pva = 0.f, pvb = 0.f;
#pragma unroll 4
    for (int j = 0; j < KTOP; ++j) {
        pva = fmaf(sW[rowA][j], Vh[(size_t)sIdx[rowA][j] * E], pva);
        pvb = fmaf(sW[rowB][j], Vh[(size_t)sIdx[rowB][j] * E], pvb);
    }
    AO[(size_t)(q0 + rowA) * E + h * D + lane] = pva / rzv[0];
    AO[(size_t)(q0 + rowB) * E + h * D + lane] = pvb / rzv[1];
}

// ---------------------------------------------------------------------------
extern "C" void kernel_launch(void* const* d_in, const int* in_sizes, int n_in,
                              void* d_out, int out_size, void* d_ws, size_t ws_size,
                              hipStream_t stream) {
    const float* x  = (const float*)d_in[0];
    const float* Wq = (const float*)d_in[1];
    const float* bq = (const float*)d_in[2];
    const float* Wk = (const float*)d_in[3];
    const float* bk = (const float*)d_in[4];
    const float* Wv = (const float*)d_in[5];
    const float* bv = (const float*)d_in[6];
    const float* Wo = (const float*)d_in[7];
    const float* bo = (const float*)d_in[8];
    float* out = (float*)d_out;

    float* Qp = (float*)d_ws;          // S*E fp32 = 8 MB each
    float* Kp = Qp + (size_t)S * E;
    float* Vp = Kp + (size_t)S * E;
    float* AO = Vp + (size_t)S * E;    // total 32 MB of ws

    const dim3 blk(256);
    gemm_nt_bias<<<dim3(E / 64, S / 64, 3), blk, 0, stream>>>(
        x, Wq, Wk, Wv, bq, bk, bv, Qp, Kp, Vp);
    topk_attn<<<dim3(S / RPB, H), blk, 0, stream>>>(Qp, Kp, Vp, AO);
    gemm_nt_bias<<<dim3(E / 64, S / 64, 1), blk, 0, stream>>>(
        AO, Wo, Wo, Wo, bo, bo, bo, out, out, out);
}

// Round 9
// 632.837 us; speedup vs baseline: 2.1530x; 2.0446x over previous
//
#include <hip/hip_runtime.h>

#define S 2048
#define E 1024
#define H 16
#define D 64
#define KTOP 64
#define RPB 8
#define SCALE 0.125f

// ---------------------------------------------------------------------------
// GEMM: C = A @ W^T + bias.  UNCHANGED (proven correct rounds 2-8); fp32
// vector-ALU, 64x64 tile, BK=32, register double-buffered staging.
// ---------------------------------------------------------------------------
__global__ __launch_bounds__(256) void gemm_nt_bias(
    const float* __restrict__ A,
    const float* __restrict__ W0, const float* __restrict__ W1, const float* __restrict__ W2,
    const float* __restrict__ b0, const float* __restrict__ b1, const float* __restrict__ b2,
    float* __restrict__ C0, float* __restrict__ C1, float* __restrict__ C2)
{
    constexpr int BM = 64, BN = 64, BK = 32;
    const int z = blockIdx.z;
    const float* W    = (z == 0) ? W0 : (z == 1) ? W1 : W2;
    const float* bias = (z == 0) ? b0 : (z == 1) ? b1 : b2;
    float*       C    = (z == 0) ? C0 : (z == 1) ? C1 : C2;

    __shared__ float As[BK][BM + 4];
    __shared__ float Bs[BK][BN + 4];

    const int tid = threadIdx.x;
    const int tx = tid & 15;
    const int ty = tid >> 4;
    const int m0 = blockIdx.y * BM;
    const int n0 = blockIdx.x * BN;

    const int r0 = tid >> 3;
    const int r1 = (tid + 256) >> 3;
    const int cq = tid & 7;

    float acc[4][4] = {};
    float4 av0, av1, wv0, wv1;

    {
        const int k0 = 0;
        av0 = *(const float4*)&A[(size_t)(m0 + r0) * E + k0 + cq * 4];
        av1 = *(const float4*)&A[(size_t)(m0 + r1) * E + k0 + cq * 4];
        wv0 = *(const float4*)&W[(size_t)(n0 + r0) * E + k0 + cq * 4];
        wv1 = *(const float4*)&W[(size_t)(n0 + r1) * E + k0 + cq * 4];
    }

    for (int k0 = 0; k0 < E; k0 += BK) {
        __syncthreads();
        As[cq * 4 + 0][r0] = av0.x; As[cq * 4 + 1][r0] = av0.y;
        As[cq * 4 + 2][r0] = av0.z; As[cq * 4 + 3][r0] = av0.w;
        As[cq * 4 + 0][r1] = av1.x; As[cq * 4 + 1][r1] = av1.y;
        As[cq * 4 + 2][r1] = av1.z; As[cq * 4 + 3][r1] = av1.w;
        Bs[cq * 4 + 0][r0] = wv0.x; Bs[cq * 4 + 1][r0] = wv0.y;
        Bs[cq * 4 + 2][r0] = wv0.z; Bs[cq * 4 + 3][r0] = wv0.w;
        Bs[cq * 4 + 0][r1] = wv1.x; Bs[cq * 4 + 1][r1] = wv1.y;
        Bs[cq * 4 + 2][r1] = wv1.z; Bs[cq * 4 + 3][r1] = wv1.w;
        __syncthreads();

        if (k0 + BK < E) {
            const int kn = k0 + BK;
            av0 = *(const float4*)&A[(size_t)(m0 + r0) * E + kn + cq * 4];
            av1 = *(const float4*)&A[(size_t)(m0 + r1) * E + kn + cq * 4];
            wv0 = *(const float4*)&W[(size_t)(n0 + r0) * E + kn + cq * 4];
            wv1 = *(const float4*)&W[(size_t)(n0 + r1) * E + kn + cq * 4];
        }

#pragma unroll
        for (int k = 0; k < BK; ++k) {
            const float4 a4 = *(const float4*)&As[k][ty * 4];
            const float4 b4 = *(const float4*)&Bs[k][tx * 4];
            const float aa[4] = {a4.x, a4.y, a4.z, a4.w};
            const float bb[4] = {b4.x, b4.y, b4.z, b4.w};
#pragma unroll
            for (int i = 0; i < 4; ++i)
#pragma unroll
                for (int j = 0; j < 4; ++j)
                    acc[i][j] = fmaf(aa[i], bb[j], acc[i][j]);
        }
    }

    const float4 bv = *(const float4*)&bias[n0 + tx * 4];
#pragma unroll
    for (int i = 0; i < 4; ++i) {
        float4 o;
        o.x = acc[i][0] + bv.x; o.y = acc[i][1] + bv.y;
        o.z = acc[i][2] + bv.z; o.w = acc[i][3] + bv.w;
        *(float4*)&C[(size_t)(m0 + ty * 4 + i) * E + n0 + tx * 4] = o;
    }
}

// ---------------------------------------------------------------------------
// Fused top-k attention, round 9.
//   Round-8 evidence: VGPR 180 (full-unroll window) -> 1 WG/CU (Occ 11.9%),
//   latency-bound scattered K loads, VALUBusy 23.6%, dur 1021us.
//   Restructure:
//   * 512 threads (8 waves): >=2 waves/SIMD even at 1 WG/CU; 2 WGs -> 4.
//   * KPL=2 keys/lane: one broadcast ds_read_b128 of Q feeds 8 FMAs
//     (4 comps x 2 keys) -> LDS pipe no longer the limiter.
//   * ib-blocked K (ka[4]/kb[4], unroll 1 on outer loops): ~90 VGPR peak,
//     fits the 128-cap allocator target with no spill.
//   * sIdx/sW overlaid into scoreBuf[row][0..127] (wave-local, su[] is in
//     regs before overwrite) -> LDS 66KB, 2 WG/CU with granularity margin.
//   Phase 2 (ballot binary-search top-64) and phase 3 (PV gather) logic
//   unchanged from the round-6/8-verified code; now 1 row per wave.
// Grid (S/8=256) x (H=16), 512 threads.
// ---------------------------------------------------------------------------
__device__ __forceinline__ unsigned sortable_u(float f) {
    unsigned u = __float_as_uint(f);
    return (u & 0x80000000u) ? ~u : (u | 0x80000000u);
}
__device__ __forceinline__ float unsortable_f(unsigned su) {
    unsigned u = (su & 0x80000000u) ? (su & 0x7fffffffu) : ~su;
    return __uint_as_float(u);
}

__global__ __launch_bounds__(512) void topk_attn(
    const float* __restrict__ Qp, const float* __restrict__ Kp,
    const float* __restrict__ Vp, float* __restrict__ AO)
{
    constexpr int THREADS = 512;
    constexpr int KPL = 2;                       // keys per lane per chunk
    constexpr int CHUNKKEYS = THREADS * KPL;     // 1024
    constexpr int NCH = S / CHUNKKEYS;           // 2

    __shared__ float scoreBuf[RPB][S];   // 64 KB (phase 2/3 overlay lives here)
    __shared__ float Qlds[RPB][D];       // 2 KB, pre-scaled Q rows

    const int tid  = threadIdx.x;
    const int lane = tid & 63;
    const int wv   = tid >> 6;          // wave 0..7
    const int h    = blockIdx.y;
    const int q0   = blockIdx.x * RPB;

    // ---- stage Q (pre-scaled), once ----
    if (tid < RPB * (D / 4)) {          // 128 threads, one float4 each
        const int r = tid >> 4, c4 = tid & 15;
        float4 qv = *(const float4*)&Qp[(size_t)(q0 + r) * E + h * D + c4 * 4];
        qv.x *= SCALE; qv.y *= SCALE; qv.z *= SCALE; qv.w *= SCALE;
        *(float4*)&Qlds[r][c4 * 4] = qv;
    }
    __syncthreads();

    // ---- Phase 1: scores.  2 chunks of 1024 keys; 2 keys per thread. ----
#pragma unroll 1
    for (int c = 0; c < NCH; ++c) {
        const int key0 = c * CHUNKKEYS + tid;          // and key0 + 512
        const float* k0p = Kp + (size_t)key0 * E + h * D;
        const float* k1p = k0p + (size_t)(THREADS) * E;

        float s0[RPB], s1[RPB];
#pragma unroll
        for (int r = 0; r < RPB; ++r) { s0[r] = 0.f; s1[r] = 0.f; }

#pragma unroll 1
        for (int ib = 0; ib < 4; ++ib) {               // 16 k-floats per ib
            float4 ka[4], kb[4];
#pragma unroll
            for (int i2 = 0; i2 < 4; ++i2)
                ka[i2] = *(const float4*)&k0p[ib * 16 + i2 * 4];
#pragma unroll
            for (int i2 = 0; i2 < 4; ++i2)
                kb[i2] = *(const float4*)&k1p[ib * 16 + i2 * 4];

#pragma unroll
            for (int i2 = 0; i2 < 4; ++i2) {
#pragma unroll
                for (int r = 0; r < RPB; ++r) {
                    // wave-uniform LDS address -> broadcast ds_read_b128,
                    // feeds 8 FMAs (4 components x 2 keys)
                    const float4 q4 = *(const float4*)&Qlds[r][ib * 16 + i2 * 4];
                    s0[r] = fmaf(q4.x, ka[i2].x, s0[r]);
                    s0[r] = fmaf(q4.y, ka[i2].y, s0[r]);
                    s0[r] = fmaf(q4.z, ka[i2].z, s0[r]);
                    s0[r] = fmaf(q4.w, ka[i2].w, s0[r]);
                    s1[r] = fmaf(q4.x, kb[i2].x, s1[r]);
                    s1[r] = fmaf(q4.y, kb[i2].y, s1[r]);
                    s1[r] = fmaf(q4.z, kb[i2].z, s1[r]);
                    s1[r] = fmaf(q4.w, kb[i2].w, s1[r]);
                }
            }
        }
#pragma unroll
        for (int r = 0; r < RPB; ++r) {
            scoreBuf[r][key0]           = s0[r];
            scoreBuf[r][key0 + THREADS] = s1[r];
        }
    }

    __syncthreads();   // all scores published; after this, row `wv` is
                       // touched only by wave `wv` (overlay is safe)

    // ---- Phase 2: wave w -> top-64 of row w ----
    const int row = wv;
    const unsigned long long below = (1ull << lane) - 1ull;

    unsigned su[32];
    unsigned mx = 0u;
#pragma unroll
    for (int j = 0; j < 32; ++j) {
        const unsigned v = sortable_u(scoreBuf[row][j * 64 + lane]);
        su[j] = v;
        if (v > mx) mx = v;
    }
    // overlay selection buffers onto this row's (already-register-resident)
    // score storage: idx in [0..63], w in [64..127]
    int*   sIdxRow = (int*)&scoreBuf[row][0];
    float* sWRow   = &scoreBuf[row][KTOP];

    // wave max
#pragma unroll
    for (int o = 32; o; o >>= 1) {
        const unsigned t = (unsigned)__shfl_xor((int)mx, o, 64);
        if (t > mx) mx = t;
    }
    const float rowmax = unsortable_f(mx);

    // bitwise binary search: T = max t with count(su >= t) >= KTOP
    unsigned T = 0u;
    for (int b = 31; b >= 0; --b) {
        const unsigned cand = T | (1u << b);
        int cnt = 0;
#pragma unroll
        for (int j = 0; j < 32; ++j)
            cnt += (int)__popcll(__ballot(su[j] >= cand));
        if (cnt >= KTOP) {
            T = cand;
            if (cnt == KTOP) break;
        }
    }

    // gather strictly-greater, then ties (==T) up to capacity.
    // enumeration order (j asc, lane asc) == ascending key -> same selected
    // SET as jax.lax.top_k (stable, lowest-index ties).
    int cprev = 0;
    float zs = 0.f;
#pragma unroll
    for (int j = 0; j < 32; ++j) {
        const bool sel = (su[j] > T);
        const unsigned long long mk = __ballot(sel);
        if (sel) {
            const int pos = cprev + (int)__popcll(mk & below);
            const float w = __expf(unsortable_f(su[j]) - rowmax);
            sIdxRow[pos] = (j << 6) | lane;
            sWRow[pos] = w;
            zs += w;
        }
        cprev += (int)__popcll(mk);
    }
#pragma unroll
    for (int j = 0; j < 32; ++j) {
        const bool sel = (su[j] == T);
        const unsigned long long mk = __ballot(sel);
        if (sel) {
            const int pos = cprev + (int)__popcll(mk & below);
            if (pos < KTOP) {
                const float w = __expf(unsortable_f(su[j]) - rowmax);
                sIdxRow[pos] = (j << 6) | lane;
                sWRow[pos] = w;
                zs += w;   // kept ties count in the denominator
            }
        }
        cprev += (int)__popcll(mk);
    }
#pragma unroll
    for (int o = 32; o; o >>= 1) zs += __shfl_xor(zs, o, 64);

    // ---- Phase 3: PV gather (wave-local) ----
    const float* Vh = Vp + h * D + lane;
    float pv = 0.f;
#pragma unroll 4
    for (int j = 0; j < KTOP; ++j) {
        pv = fmaf(sWRow[j], Vh[(size_t)sIdxRow[j] * E], pv);
    }
    AO[(size_t)(q0 + row) * E + h * D + lane] = pv / zs;
}

// ---------------------------------------------------------------------------
extern "C" void kernel_launch(void* const* d_in, const int* in_sizes, int n_in,
                              void* d_out, int out_size, void* d_ws, size_t ws_size,
                              hipStream_t stream) {
    const float* x  = (const float*)d_in[0];
    const float* Wq = (const float*)d_in[1];
    const float* bq = (const float*)d_in[2];
    const float* Wk = (const float*)d_in[3];
    const float* bk = (const float*)d_in[4];
    const float* Wv = (const float*)d_in[5];
    const float* bv = (const float*)d_in[6];
    const float* Wo = (const float*)d_in[7];
    const float* bo = (const float*)d_in[8];
    float* out = (float*)d_out;

    float* Qp = (float*)d_ws;          // S*E fp32 = 8 MB each
    float* Kp = Qp + (size_t)S * E;
    float* Vp = Kp + (size_t)S * E;
    float* AO = Vp + (size_t)S * E;    // total 32 MB of ws

    gemm_nt_bias<<<dim3(E / 64, S / 64, 3), dim3(256), 0, stream>>>(
        x, Wq, Wk, Wv, bq, bk, bv, Qp, Kp, Vp);
    topk_attn<<<dim3(S / RPB, H), dim3(512), 0, stream>>>(Qp, Kp, Vp, AO);
    gemm_nt_bias<<<dim3(E / 64, S / 64, 1), dim3(256), 0, stream>>>(
        AO, Wo, Wo, Wo, bo, bo, bo, out, out, out);
}